// Round 1
// baseline (453.830 us; speedup 1.0000x reference)
//
#include <hip/hip_runtime.h>

// Problem sizes
#define NROWS 8192   // B*T
#define MCB   1024   // codebook size M
#define DD    256    // feature dim D
#define TT    128    // T
#define BB    64     // B

// ws offsets (in floats)
#define OFF_DA      0ul
#define OFF_DV      8388608ul
#define OFF_XX_A    16777216ul
#define OFF_XX_V    16785408ul
#define OFF_EE      16793600ul
#define OFF_SMIN_A  16794624ul
#define OFF_LZ1_A   16802816ul
#define OFF_IZ2_A   16811008ul
#define OFF_IDX_A   16819200ul
#define OFF_SMIN_V  16827392ul
#define OFF_LZ1_V   16835584ul
#define OFF_IZ2_V   16843776ul
#define OFF_IDX_V   16851968ul
#define OFF_S1      16860160ul
#define OFF_S2      17384448ul
#define OFF_PART    17908736ul
#define OFF_MAX     17908992ul
#define OFF_ACC     17908994ul
// total ~17,908,996 floats = ~71.6 MB of ws

// ---------------------------------------------------------------------------
// Kernel 1: row sums of squares (fp64 accumulate for accuracy): xx_a, xx_v, ee
// One wave per row (256 floats = 64 lanes x float4).
__global__ void k_sumsq(const float* __restrict__ A, const float* __restrict__ V,
                        const float* __restrict__ E, float* __restrict__ ws) {
  const int lane = threadIdx.x & 63;
  const int wid  = threadIdx.x >> 6;
  const int row = blockIdx.x * 4 + wid;   // 0..17407
  const float* src; float* dst; int r;
  if (row < 8192)       { src = A; r = row;         dst = ws + OFF_XX_A; }
  else if (row < 16384) { src = V; r = row - 8192;  dst = ws + OFF_XX_V; }
  else                  { src = E; r = row - 16384; dst = ws + OFF_EE; }
  float4 x = *(const float4*)(src + (size_t)r * DD + lane * 4);
  double acc = (double)x.x * x.x + (double)x.y * x.y +
               (double)x.z * x.z + (double)x.w * x.w;
  #pragma unroll
  for (int off = 32; off; off >>= 1) acc += __shfl_xor(acc, off);
  if (lane == 0) dst[r] = (float)acc;
}

// ---------------------------------------------------------------------------
// Kernel 2: dist GEMM. d[n,m] = (ee[m] + xx[n]) - 2 * (x[n,:] . e[m,:])
// 64x64 C-tile per 256-thread block, 4x4 per thread, K-chunks of 32.
__global__ __launch_bounds__(256) void k_dist(const float* __restrict__ A,
    const float* __restrict__ V, const float* __restrict__ E,
    float* __restrict__ ws) {
  const int z = blockIdx.z;
  const float* X  = z ? V : A;
  const float* xx = ws + (z ? OFF_XX_V : OFF_XX_A);
  const float* ee = ws + OFF_EE;
  float* Dst = ws + (z ? OFF_DV : OFF_DA);

  __shared__ __align__(16) float As[32][68];
  __shared__ __align__(16) float Bs[32][68];

  const int tid = threadIdx.x;
  const int tx = tid & 15, ty = tid >> 4;
  const int row0 = blockIdx.y * 64;
  const int col0 = blockIdx.x * 64;

  float acc[4][4] = {};

  for (int kc = 0; kc < 256; kc += 32) {
    #pragma unroll
    for (int i = 0; i < 2; ++i) {
      int f  = tid * 2 + i;        // 0..511
      int r  = f >> 3;             // 0..63
      int k4 = (f & 7) << 2;       // 0,4,..,28
      float4 a = *(const float4*)(X + (size_t)(row0 + r) * DD + kc + k4);
      As[k4+0][r] = a.x; As[k4+1][r] = a.y; As[k4+2][r] = a.z; As[k4+3][r] = a.w;
      float4 b = *(const float4*)(E + (size_t)(col0 + r) * DD + kc + k4);
      Bs[k4+0][r] = b.x; Bs[k4+1][r] = b.y; Bs[k4+2][r] = b.z; Bs[k4+3][r] = b.w;
    }
    __syncthreads();
    #pragma unroll
    for (int k = 0; k < 32; ++k) {
      float4 av = *(const float4*)(&As[k][ty << 2]);
      float4 bv = *(const float4*)(&Bs[k][tx << 2]);
      float aa[4] = {av.x, av.y, av.z, av.w};
      float bb[4] = {bv.x, bv.y, bv.z, bv.w};
      #pragma unroll
      for (int i = 0; i < 4; ++i)
        #pragma unroll
        for (int j = 0; j < 4; ++j)
          acc[i][j] = fmaf(aa[i], bb[j], acc[i][j]);
    }
    __syncthreads();
  }

  float er[4];
  #pragma unroll
  for (int j = 0; j < 4; ++j) er[j] = ee[col0 + (tx << 2) + j];
  #pragma unroll
  for (int i = 0; i < 4; ++i) {
    float xri = xx[row0 + (ty << 2) + i];
    float4 o;
    o.x = (er[0] + xri) - 2.0f * acc[i][0];
    o.y = (er[1] + xri) - 2.0f * acc[i][1];
    o.z = (er[2] + xri) - 2.0f * acc[i][2];
    o.w = (er[3] + xri) - 2.0f * acc[i][3];
    *(float4*)(Dst + (size_t)(row0 + (ty << 2) + i) * MCB + col0 + (tx << 2)) = o;
  }
}

// ---------------------------------------------------------------------------
// Kernel 3: per-row stats (min/argmin, softmax denominators) + quantize write.
// One wave per row; each lane holds 16 d-values in registers.
__global__ void k_rowstats(const float* __restrict__ A, const float* __restrict__ V,
                           const float* __restrict__ E, float* __restrict__ ws,
                           float* __restrict__ out) {
  const int z = blockIdx.y;
  const float* Dm = ws + (z ? OFF_DV : OFF_DA);
  const float* X  = z ? V : A;
  float* smin_o = ws + (z ? OFF_SMIN_V : OFF_SMIN_A);
  float* lz1_o  = ws + (z ? OFF_LZ1_V  : OFF_LZ1_A);
  float* iz2_o  = ws + (z ? OFF_IZ2_V  : OFF_IZ2_A);
  int*   idx_o  = (int*)(ws + (z ? OFF_IDX_V : OFF_IDX_A));
  float* qout = out + 1 + (size_t)z * ((size_t)NROWS * DD);

  const int lane = threadIdx.x & 63, wid = threadIdx.x >> 6;
  const int n = blockIdx.x * 4 + wid;
  const float* drow = Dm + (size_t)n * MCB;

  float v[16];
  #pragma unroll
  for (int c = 0; c < 4; ++c) {
    float4 t = *(const float4*)(drow + c * 256 + lane * 4);
    v[c*4+0] = t.x; v[c*4+1] = t.y; v[c*4+2] = t.z; v[c*4+3] = t.w;
  }
  // argmin with first-index tie-break (matches jnp.argmin)
  float bv = 3.4e38f; int bi = 0;
  #pragma unroll
  for (int c = 0; c < 4; ++c)
    #pragma unroll
    for (int j = 0; j < 4; ++j) {
      float val = v[c*4+j];
      int m = c * 256 + lane * 4 + j;
      if (val < bv) { bv = val; bi = m; }
    }
  #pragma unroll
  for (int off = 32; off; off >>= 1) {
    float ov = __shfl_xor(bv, off);
    int   oi = __shfl_xor(bi, off);
    if (ov < bv || (ov == bv && oi < bi)) { bv = ov; bi = oi; }
  }
  float smin = sqrtf(fmaxf(bv, 0.0f));
  float z1 = 0.f, z2 = 0.f;
  #pragma unroll
  for (int q = 0; q < 16; ++q) {
    float w = sqrtf(fmaxf(v[q], 0.0f)) - smin;
    z1 += expf(-w);
    z2 += expf(-2.0f * w);
  }
  #pragma unroll
  for (int off = 32; off; off >>= 1) {
    z1 += __shfl_xor(z1, off);
    z2 += __shfl_xor(z2, off);
  }
  if (lane == 0) {
    smin_o[n] = smin;
    lz1_o[n]  = logf(z1);
    iz2_o[n]  = 1.0f / z2;
    idx_o[n]  = bi;
  }
  // quantized output: x + (e[idx] - x), scalar phases (out+1 is only 4B-aligned)
  const float* erow = E + (size_t)bi * DD;
  const float* xrow = X + (size_t)n * DD;
  #pragma unroll
  for (int p = 0; p < 4; ++p) {
    int d0 = p * 64 + lane;
    float xv = xrow[d0];
    float ev = erow[d0];
    qout[(size_t)n * DD + d0] = xv + (ev - xv);
  }
}

// ---------------------------------------------------------------------------
// Kernel 4: S[t,b,c] = sum_m adj_p[b*T+t, m] * logq[c*T+t, m]
// One block per (t, which); m-chunks of 64 staged in LDS with on-the-fly
// softmax/log transforms; 4x4 per thread over the 64x64 output.
__global__ __launch_bounds__(256) void k_sgemm(float* __restrict__ ws) {
  const int z = blockIdx.y;   // 0: (adjA, log pHv) -> S1 ; 1: (adjV, log pHa) -> S2
  const int t = blockIdx.x;
  const float* Dp = ws + (z ? OFF_DV : OFF_DA);
  const float* Dq = ws + (z ? OFF_DA : OFF_DV);
  const float* smin_p = ws + (z ? OFF_SMIN_V : OFF_SMIN_A);
  const float* iz2_p  = ws + (z ? OFF_IZ2_V  : OFF_IZ2_A);
  const float* smin_q = ws + (z ? OFF_SMIN_A : OFF_SMIN_V);
  const float* lz1_q  = ws + (z ? OFF_LZ1_A  : OFF_LZ1_V);
  float* S = ws + (z ? OFF_S2 : OFF_S1);

  __shared__ __align__(16) float PA[64][68];
  __shared__ __align__(16) float LQ[64][68];
  __shared__ float sP[64], izP[64], sQ[64], lzQ[64];

  const int tid = threadIdx.x;
  const int tx = tid & 15, ty = tid >> 4;
  const int lm = tid & 63, wq = tid >> 6;

  if (tid < 64) {
    size_t n = (size_t)tid * TT + t;
    sP[tid] = smin_p[n]; izP[tid] = iz2_p[n];
    sQ[tid] = smin_q[n]; lzQ[tid] = lz1_q[n];
  }
  __syncthreads();

  float acc[4][4] = {};
  for (int mc = 0; mc < MCB; mc += 64) {
    #pragma unroll
    for (int i = 0; i < 16; ++i) {
      int b = i * 4 + wq;               // 0..63, each exactly once
      size_t n = (size_t)b * TT + t;
      float dp = Dp[n * MCB + mc + lm];
      float wp = sqrtf(fmaxf(dp, 0.f)) - sP[b];
      PA[lm][b] = expf(-2.f * wp) * izP[b];
      float dq = Dq[n * MCB + mc + lm];
      float wv = sqrtf(fmaxf(dq, 0.f)) - sQ[b];
      LQ[lm][b] = -wv - lzQ[b];
    }
    __syncthreads();
    #pragma unroll
    for (int mm = 0; mm < 64; ++mm) {
      float4 av = *(const float4*)(&PA[mm][ty << 2]);
      float4 bv = *(const float4*)(&LQ[mm][tx << 2]);
      float aa[4] = {av.x, av.y, av.z, av.w};
      float bb[4] = {bv.x, bv.y, bv.z, bv.w};
      #pragma unroll
      for (int i = 0; i < 4; ++i)
        #pragma unroll
        for (int j = 0; j < 4; ++j)
          acc[i][j] = fmaf(aa[i], bb[j], acc[i][j]);
    }
    __syncthreads();
  }
  #pragma unroll
  for (int i = 0; i < 4; ++i) {
    float4 o = {acc[i][0], acc[i][1], acc[i][2], acc[i][3]};
    *(float4*)(S + ((size_t)t * 64 + (ty << 2) + i) * 64 + (tx << 2)) = o;
  }
}

// ---------------------------------------------------------------------------
// Kernel 5a: partial min over S1/S2
__global__ void k_smin(float* __restrict__ ws) {
  const float* S = ws + (blockIdx.y ? OFF_S2 : OFF_S1);
  float* part = ws + OFF_PART;
  size_t base = (size_t)blockIdx.x * 4096;
  float m = 3.4e38f;
  for (int i = threadIdx.x; i < 4096; i += 256) m = fminf(m, S[base + i]);
  #pragma unroll
  for (int off = 32; off; off >>= 1) m = fminf(m, __shfl_xor(m, off));
  __shared__ float red[4];
  const int lane = threadIdx.x & 63, wid = threadIdx.x >> 6;
  if (lane == 0) red[wid] = m;
  __syncthreads();
  if (threadIdx.x == 0)
    part[blockIdx.y * 128 + blockIdx.x] =
        fminf(fminf(red[0], red[1]), fminf(red[2], red[3]));
}

// Kernel 5b: final max(-S) per tensor + zero the loss accumulators
__global__ void k_sfinal(float* __restrict__ ws) {
  const float* part = ws + OFF_PART;
  float* maxv = ws + OFF_MAX;
  float* acc  = ws + OFF_ACC;
  const int tens = threadIdx.x >> 7;
  const int i = threadIdx.x & 127;
  float m = part[tens * 128 + i];
  #pragma unroll
  for (int off = 32; off; off >>= 1) m = fminf(m, __shfl_xor(m, off));
  __shared__ float red[4];
  const int lane = threadIdx.x & 63, wid = threadIdx.x >> 6;
  if (lane == 0) red[wid] = m;
  __syncthreads();
  if (threadIdx.x == 0)   { maxv[0] = -fminf(red[0], red[1]); acc[0] = 0.f; }
  if (threadIdx.x == 128) { maxv[1] = -fminf(red[2], red[3]); acc[1] = 0.f; }
}

// ---------------------------------------------------------------------------
// Kernel 6: per-(tensor,t,b) row: E=exp(S+Max), diag/(rowsum+eps), accumulate log
__global__ void k_loss(float* __restrict__ ws) {
  const int lane = threadIdx.x & 63, wid = threadIdx.x >> 6;
  const int gw = blockIdx.x * 4 + wid;   // 0..16383
  const int tens = gw >> 13;
  const int rem = gw & 8191;             // t*64 + b
  const float* S = ws + (tens ? OFF_S2 : OFF_S1);
  const float maxv = (ws + OFF_MAX)[tens];
  float ev = expf(S[(size_t)rem * 64 + lane] + maxv);
  float sum = ev;
  #pragma unroll
  for (int off = 32; off; off >>= 1) sum += __shfl_xor(sum, off);
  const int b = rem & 63;
  float diag = __shfl(ev, b);
  if (lane == 0) atomicAdd((ws + OFF_ACC) + tens, logf(diag / (sum + 1e-5f)));
}

// Kernel 7: finalize loss
__global__ void k_fin(const float* __restrict__ ws, float* __restrict__ out) {
  out[0] = -((ws + OFF_ACC)[0] + (ws + OFF_ACC)[1]) / 16384.0f;
}

// ---------------------------------------------------------------------------
extern "C" void kernel_launch(void* const* d_in, const int* in_sizes, int n_in,
                              void* d_out, int out_size, void* d_ws, size_t ws_size,
                              hipStream_t stream) {
  const float* A = (const float*)d_in[0];
  const float* V = (const float*)d_in[1];
  const float* E = (const float*)d_in[2];
  float* out = (float*)d_out;
  float* ws  = (float*)d_ws;

  k_sumsq  <<<dim3(4352), dim3(256), 0, stream>>>(A, V, E, ws);
  k_dist   <<<dim3(16, 128, 2), dim3(256), 0, stream>>>(A, V, E, ws);
  k_rowstats<<<dim3(2048, 2), dim3(256), 0, stream>>>(A, V, E, ws, out);
  k_sgemm  <<<dim3(128, 2), dim3(256), 0, stream>>>(ws);
  k_smin   <<<dim3(128, 2), dim3(256), 0, stream>>>(ws);
  k_sfinal <<<dim3(1), dim3(256), 0, stream>>>(ws);
  k_loss   <<<dim3(4096), dim3(256), 0, stream>>>(ws);
  k_fin    <<<dim3(1), dim3(1), 0, stream>>>(ws, out);
}

// Round 2
// 240.949 us; speedup vs baseline: 1.8835x; 1.8835x over previous
//
#include <hip/hip_runtime.h>

// Problem sizes
#define NROWS 8192   // B*T
#define MCB   1024   // codebook size M
#define DD    256    // feature dim D
#define TT    128    // T
#define BB    64     // B

// ws offsets (in floats)
#define OFF_DA      0ul
#define OFF_DV      8388608ul
#define OFF_XX_A    16777216ul
#define OFF_XX_V    16785408ul
#define OFF_EE      16793600ul
#define OFF_SMIN_A  16794624ul
#define OFF_LZ1_A   16802816ul
#define OFF_IZ2_A   16811008ul
#define OFF_IDX_A   16819200ul
#define OFF_SMIN_V  16827392ul
#define OFF_LZ1_V   16835584ul
#define OFF_IZ2_V   16843776ul
#define OFF_IDX_V   16851968ul
#define OFF_S1      16860160ul
#define OFF_S2      17384448ul
#define OFF_PART    17908736ul
#define OFF_MAX     17908992ul
#define OFF_PACC    17909000ul   // 256 doubles (8-byte aligned), per-block loss partials
// total ~17,909,512 floats = ~71.6 MB of ws

// ---------------------------------------------------------------------------
// Kernel 1: row sums of squares (fp64 accumulate for accuracy): xx_a, xx_v, ee
// One wave per row (256 floats = 64 lanes x float4).
__global__ void k_sumsq(const float* __restrict__ A, const float* __restrict__ V,
                        const float* __restrict__ E, float* __restrict__ ws) {
  const int lane = threadIdx.x & 63;
  const int wid  = threadIdx.x >> 6;
  const int row = blockIdx.x * 4 + wid;   // 0..17407
  const float* src; float* dst; int r;
  if (row < 8192)       { src = A; r = row;         dst = ws + OFF_XX_A; }
  else if (row < 16384) { src = V; r = row - 8192;  dst = ws + OFF_XX_V; }
  else                  { src = E; r = row - 16384; dst = ws + OFF_EE; }
  float4 x = *(const float4*)(src + (size_t)r * DD + lane * 4);
  double acc = (double)x.x * x.x + (double)x.y * x.y +
               (double)x.z * x.z + (double)x.w * x.w;
  #pragma unroll
  for (int off = 32; off; off >>= 1) acc += __shfl_xor(acc, off);
  if (lane == 0) dst[r] = (float)acc;
}

// ---------------------------------------------------------------------------
// Kernel 2: dist GEMM. d[n,m] = (ee[m] + xx[n]) - 2 * (x[n,:] . e[m,:])
// 64x64 C-tile per 256-thread block, 4x4 per thread, K-chunks of 32.
__global__ __launch_bounds__(256) void k_dist(const float* __restrict__ A,
    const float* __restrict__ V, const float* __restrict__ E,
    float* __restrict__ ws) {
  const int z = blockIdx.z;
  const float* X  = z ? V : A;
  const float* xx = ws + (z ? OFF_XX_V : OFF_XX_A);
  const float* ee = ws + OFF_EE;
  float* Dst = ws + (z ? OFF_DV : OFF_DA);

  __shared__ __align__(16) float As[32][68];
  __shared__ __align__(16) float Bs[32][68];

  const int tid = threadIdx.x;
  const int tx = tid & 15, ty = tid >> 4;
  const int row0 = blockIdx.y * 64;
  const int col0 = blockIdx.x * 64;

  float acc[4][4] = {};

  for (int kc = 0; kc < 256; kc += 32) {
    #pragma unroll
    for (int i = 0; i < 2; ++i) {
      int f  = tid * 2 + i;        // 0..511
      int r  = f >> 3;             // 0..63
      int k4 = (f & 7) << 2;       // 0,4,..,28
      float4 a = *(const float4*)(X + (size_t)(row0 + r) * DD + kc + k4);
      As[k4+0][r] = a.x; As[k4+1][r] = a.y; As[k4+2][r] = a.z; As[k4+3][r] = a.w;
      float4 b = *(const float4*)(E + (size_t)(col0 + r) * DD + kc + k4);
      Bs[k4+0][r] = b.x; Bs[k4+1][r] = b.y; Bs[k4+2][r] = b.z; Bs[k4+3][r] = b.w;
    }
    __syncthreads();
    #pragma unroll
    for (int k = 0; k < 32; ++k) {
      float4 av = *(const float4*)(&As[k][ty << 2]);
      float4 bv = *(const float4*)(&Bs[k][tx << 2]);
      float aa[4] = {av.x, av.y, av.z, av.w};
      float bb[4] = {bv.x, bv.y, bv.z, bv.w};
      #pragma unroll
      for (int i = 0; i < 4; ++i)
        #pragma unroll
        for (int j = 0; j < 4; ++j)
          acc[i][j] = fmaf(aa[i], bb[j], acc[i][j]);
    }
    __syncthreads();
  }

  float er[4];
  #pragma unroll
  for (int j = 0; j < 4; ++j) er[j] = ee[col0 + (tx << 2) + j];
  #pragma unroll
  for (int i = 0; i < 4; ++i) {
    float xri = xx[row0 + (ty << 2) + i];
    float4 o;
    o.x = (er[0] + xri) - 2.0f * acc[i][0];
    o.y = (er[1] + xri) - 2.0f * acc[i][1];
    o.z = (er[2] + xri) - 2.0f * acc[i][2];
    o.w = (er[3] + xri) - 2.0f * acc[i][3];
    *(float4*)(Dst + (size_t)(row0 + (ty << 2) + i) * MCB + col0 + (tx << 2)) = o;
  }
}

// ---------------------------------------------------------------------------
// Kernel 3: per-row stats (min/argmin, softmax denominators) + quantize write.
// One wave per row; each lane holds 16 d-values in registers.
__global__ void k_rowstats(const float* __restrict__ A, const float* __restrict__ V,
                           const float* __restrict__ E, float* __restrict__ ws,
                           float* __restrict__ out) {
  const int z = blockIdx.y;
  const float* Dm = ws + (z ? OFF_DV : OFF_DA);
  const float* X  = z ? V : A;
  float* smin_o = ws + (z ? OFF_SMIN_V : OFF_SMIN_A);
  float* lz1_o  = ws + (z ? OFF_LZ1_V  : OFF_LZ1_A);
  float* iz2_o  = ws + (z ? OFF_IZ2_V  : OFF_IZ2_A);
  int*   idx_o  = (int*)(ws + (z ? OFF_IDX_V : OFF_IDX_A));
  float* qout = out + 1 + (size_t)z * ((size_t)NROWS * DD);

  const int lane = threadIdx.x & 63, wid = threadIdx.x >> 6;
  const int n = blockIdx.x * 4 + wid;
  const float* drow = Dm + (size_t)n * MCB;

  float v[16];
  #pragma unroll
  for (int c = 0; c < 4; ++c) {
    float4 t = *(const float4*)(drow + c * 256 + lane * 4);
    v[c*4+0] = t.x; v[c*4+1] = t.y; v[c*4+2] = t.z; v[c*4+3] = t.w;
  }
  // argmin with first-index tie-break (matches jnp.argmin)
  float bv = 3.4e38f; int bi = 0;
  #pragma unroll
  for (int c = 0; c < 4; ++c)
    #pragma unroll
    for (int j = 0; j < 4; ++j) {
      float val = v[c*4+j];
      int m = c * 256 + lane * 4 + j;
      if (val < bv) { bv = val; bi = m; }
    }
  #pragma unroll
  for (int off = 32; off; off >>= 1) {
    float ov = __shfl_xor(bv, off);
    int   oi = __shfl_xor(bi, off);
    if (ov < bv || (ov == bv && oi < bi)) { bv = ov; bi = oi; }
  }
  float smin = sqrtf(fmaxf(bv, 0.0f));
  float z1 = 0.f, z2 = 0.f;
  #pragma unroll
  for (int q = 0; q < 16; ++q) {
    float w = sqrtf(fmaxf(v[q], 0.0f)) - smin;
    z1 += expf(-w);
    z2 += expf(-2.0f * w);
  }
  #pragma unroll
  for (int off = 32; off; off >>= 1) {
    z1 += __shfl_xor(z1, off);
    z2 += __shfl_xor(z2, off);
  }
  if (lane == 0) {
    smin_o[n] = smin;
    lz1_o[n]  = logf(z1);
    iz2_o[n]  = 1.0f / z2;
    idx_o[n]  = bi;
  }
  // quantized output: x + (e[idx] - x), scalar phases (out+1 is only 4B-aligned)
  const float* erow = E + (size_t)bi * DD;
  const float* xrow = X + (size_t)n * DD;
  #pragma unroll
  for (int p = 0; p < 4; ++p) {
    int d0 = p * 64 + lane;
    float xv = xrow[d0];
    float ev = erow[d0];
    qout[(size_t)n * DD + d0] = xv + (ev - xv);
  }
}

// ---------------------------------------------------------------------------
// Kernel 4: S[t,b,c] = sum_m adj_p[b*T+t, m] * logq[c*T+t, m]
// One block per (t, which); m-chunks of 64 staged in LDS with on-the-fly
// softmax/log transforms; 4x4 per thread over the 64x64 output.
__global__ __launch_bounds__(256) void k_sgemm(float* __restrict__ ws) {
  const int z = blockIdx.y;   // 0: (adjA, log pHv) -> S1 ; 1: (adjV, log pHa) -> S2
  const int t = blockIdx.x;
  const float* Dp = ws + (z ? OFF_DV : OFF_DA);
  const float* Dq = ws + (z ? OFF_DA : OFF_DV);
  const float* smin_p = ws + (z ? OFF_SMIN_V : OFF_SMIN_A);
  const float* iz2_p  = ws + (z ? OFF_IZ2_V  : OFF_IZ2_A);
  const float* smin_q = ws + (z ? OFF_SMIN_A : OFF_SMIN_V);
  const float* lz1_q  = ws + (z ? OFF_LZ1_A  : OFF_LZ1_V);
  float* S = ws + (z ? OFF_S2 : OFF_S1);

  __shared__ __align__(16) float PA[64][68];
  __shared__ __align__(16) float LQ[64][68];
  __shared__ float sP[64], izP[64], sQ[64], lzQ[64];

  const int tid = threadIdx.x;
  const int tx = tid & 15, ty = tid >> 4;
  const int lm = tid & 63, wq = tid >> 6;

  if (tid < 64) {
    size_t n = (size_t)tid * TT + t;
    sP[tid] = smin_p[n]; izP[tid] = iz2_p[n];
    sQ[tid] = smin_q[n]; lzQ[tid] = lz1_q[n];
  }
  __syncthreads();

  float acc[4][4] = {};
  for (int mc = 0; mc < MCB; mc += 64) {
    #pragma unroll
    for (int i = 0; i < 16; ++i) {
      int b = i * 4 + wq;               // 0..63, each exactly once
      size_t n = (size_t)b * TT + t;
      float dp = Dp[n * MCB + mc + lm];
      float wp = sqrtf(fmaxf(dp, 0.f)) - sP[b];
      PA[lm][b] = expf(-2.f * wp) * izP[b];
      float dq = Dq[n * MCB + mc + lm];
      float wv = sqrtf(fmaxf(dq, 0.f)) - sQ[b];
      LQ[lm][b] = -wv - lzQ[b];
    }
    __syncthreads();
    #pragma unroll
    for (int mm = 0; mm < 64; ++mm) {
      float4 av = *(const float4*)(&PA[mm][ty << 2]);
      float4 bv = *(const float4*)(&LQ[mm][tx << 2]);
      float aa[4] = {av.x, av.y, av.z, av.w};
      float bb[4] = {bv.x, bv.y, bv.z, bv.w};
      #pragma unroll
      for (int i = 0; i < 4; ++i)
        #pragma unroll
        for (int j = 0; j < 4; ++j)
          acc[i][j] = fmaf(aa[i], bb[j], acc[i][j]);
    }
    __syncthreads();
  }
  #pragma unroll
  for (int i = 0; i < 4; ++i) {
    float4 o = {acc[i][0], acc[i][1], acc[i][2], acc[i][3]};
    *(float4*)(S + ((size_t)t * 64 + (ty << 2) + i) * 64 + (tx << 2)) = o;
  }
}

// ---------------------------------------------------------------------------
// Kernel 5a: partial min over S1/S2
__global__ void k_smin(float* __restrict__ ws) {
  const float* S = ws + (blockIdx.y ? OFF_S2 : OFF_S1);
  float* part = ws + OFF_PART;
  size_t base = (size_t)blockIdx.x * 4096;
  float m = 3.4e38f;
  for (int i = threadIdx.x; i < 4096; i += 256) m = fminf(m, S[base + i]);
  #pragma unroll
  for (int off = 32; off; off >>= 1) m = fminf(m, __shfl_xor(m, off));
  __shared__ float red[4];
  const int lane = threadIdx.x & 63, wid = threadIdx.x >> 6;
  if (lane == 0) red[wid] = m;
  __syncthreads();
  if (threadIdx.x == 0)
    part[blockIdx.y * 128 + blockIdx.x] =
        fminf(fminf(red[0], red[1]), fminf(red[2], red[3]));
}

// Kernel 5b: final max(-S) per tensor
__global__ void k_sfinal(float* __restrict__ ws) {
  const float* part = ws + OFF_PART;
  float* maxv = ws + OFF_MAX;
  const int tens = threadIdx.x >> 7;
  const int i = threadIdx.x & 127;
  float m = part[tens * 128 + i];
  #pragma unroll
  for (int off = 32; off; off >>= 1) m = fminf(m, __shfl_xor(m, off));
  __shared__ float red[4];
  const int lane = threadIdx.x & 63, wid = threadIdx.x >> 6;
  if (lane == 0) red[wid] = m;
  __syncthreads();
  if (threadIdx.x == 0)   maxv[0] = -fminf(red[0], red[1]);
  if (threadIdx.x == 128) maxv[1] = -fminf(red[2], red[3]);
}

// ---------------------------------------------------------------------------
// Kernel 6: per-(tensor,t,b) row: E=exp(S+Max), log(diag/(rowsum+eps));
// per-wave register accumulation (16 rows/wave), per-block partial -> no atomics.
__global__ __launch_bounds__(256) void k_loss(float* __restrict__ ws) {
  const int lane = threadIdx.x & 63, wid = threadIdx.x >> 6;
  const int wglobal = blockIdx.x * 4 + wid;   // 0..1023
  const float* Smax = ws + OFF_MAX;
  double acc = 0.0;
  #pragma unroll 4
  for (int r = 0; r < 16; ++r) {
    int gw = wglobal * 16 + r;                // 0..16383
    int tens = gw >> 13;
    int rem = gw & 8191;                      // t*64 + b
    const float* S = ws + (tens ? OFF_S2 : OFF_S1);
    float maxv = Smax[tens];
    float ev = expf(S[(size_t)rem * 64 + lane] + maxv);
    float sum = ev;
    #pragma unroll
    for (int off = 32; off; off >>= 1) sum += __shfl_xor(sum, off);
    float diag = __shfl(ev, rem & 63);
    if (lane == 0) acc += (double)logf(diag / (sum + 1e-5f));
  }
  __shared__ double red[4];
  if (lane == 0) red[wid] = acc;
  __syncthreads();
  if (threadIdx.x == 0)
    ((double*)(ws + OFF_PACC))[blockIdx.x] = red[0] + red[1] + red[2] + red[3];
}

// Kernel 7: reduce 256 per-block partials, finalize loss
__global__ void k_fin(const float* __restrict__ ws, float* __restrict__ out) {
  const double* p = (const double*)(ws + OFF_PACC);
  const int lane = threadIdx.x & 63, wid = threadIdx.x >> 6;
  double v = p[threadIdx.x];
  #pragma unroll
  for (int off = 32; off; off >>= 1) v += __shfl_xor(v, off);
  __shared__ double red[4];
  if (lane == 0) red[wid] = v;
  __syncthreads();
  if (threadIdx.x == 0)
    out[0] = (float)(-(red[0] + red[1] + red[2] + red[3]) / 16384.0);
}

// ---------------------------------------------------------------------------
extern "C" void kernel_launch(void* const* d_in, const int* in_sizes, int n_in,
                              void* d_out, int out_size, void* d_ws, size_t ws_size,
                              hipStream_t stream) {
  const float* A = (const float*)d_in[0];
  const float* V = (const float*)d_in[1];
  const float* E = (const float*)d_in[2];
  float* out = (float*)d_out;
  float* ws  = (float*)d_ws;

  k_sumsq  <<<dim3(4352), dim3(256), 0, stream>>>(A, V, E, ws);
  k_dist   <<<dim3(16, 128, 2), dim3(256), 0, stream>>>(A, V, E, ws);
  k_rowstats<<<dim3(2048, 2), dim3(256), 0, stream>>>(A, V, E, ws, out);
  k_sgemm  <<<dim3(128, 2), dim3(256), 0, stream>>>(ws);
  k_smin   <<<dim3(128, 2), dim3(256), 0, stream>>>(ws);
  k_sfinal <<<dim3(1), dim3(256), 0, stream>>>(ws);
  k_loss   <<<dim3(256), dim3(256), 0, stream>>>(ws);
  k_fin    <<<dim3(1), dim3(256), 0, stream>>>(ws, out);
}

// Round 3
// 240.671 us; speedup vs baseline: 1.8857x; 1.0012x over previous
//
#include <hip/hip_runtime.h>

// Problem sizes
#define NROWS 8192   // B*T
#define MCB   1024   // codebook size M
#define DD    256    // feature dim D
#define TT    128    // T
#define BB    64     // B

// ws offsets (in floats)
#define OFF_DA      0ul
#define OFF_DV      8388608ul
#define OFF_XX_A    16777216ul
#define OFF_XX_V    16785408ul
#define OFF_EE      16793600ul
#define OFF_SMIN_A  16794624ul
#define OFF_LZ1_A   16802816ul
#define OFF_IZ2_A   16811008ul
#define OFF_IDX_A   16819200ul
#define OFF_SMIN_V  16827392ul
#define OFF_LZ1_V   16835584ul
#define OFF_IZ2_V   16843776ul
#define OFF_IDX_V   16851968ul
#define OFF_S1      16860160ul
#define OFF_S2      17384448ul
#define OFF_PART    17908736ul
#define OFF_MAX     17908992ul
#define OFF_PACC    17909000ul   // 256 doubles (8-byte aligned), per-block loss partials

// ---------------------------------------------------------------------------
// Kernel 1: row sums of squares (fp64 accumulate for accuracy): xx_a, xx_v, ee
__global__ void k_sumsq(const float* __restrict__ A, const float* __restrict__ V,
                        const float* __restrict__ E, float* __restrict__ ws) {
  const int lane = threadIdx.x & 63;
  const int wid  = threadIdx.x >> 6;
  const int row = blockIdx.x * 4 + wid;   // 0..17407
  const float* src; float* dst; int r;
  if (row < 8192)       { src = A; r = row;         dst = ws + OFF_XX_A; }
  else if (row < 16384) { src = V; r = row - 8192;  dst = ws + OFF_XX_V; }
  else                  { src = E; r = row - 16384; dst = ws + OFF_EE; }
  float4 x = *(const float4*)(src + (size_t)r * DD + lane * 4);
  double acc = (double)x.x * x.x + (double)x.y * x.y +
               (double)x.z * x.z + (double)x.w * x.w;
  #pragma unroll
  for (int off = 32; off; off >>= 1) acc += __shfl_xor(acc, off);
  if (lane == 0) dst[r] = (float)acc;
}

// ---------------------------------------------------------------------------
// Kernel 2: dist GEMM. d[n,m] = (ee[m] + xx[n]) - 2 * (x[n,:] . e[m,:])
// 128x128 C-tile per 256-thread block, 8x8 per thread, K-chunks of 32.
// LDS layout: As[k][row] (reads broadcast across 16 lanes -> conflict-free);
// Bs[k][phys(col)] with phys = col + 4*(col>>5) -> 16 lane-addresses land
// 2-way per bank-quad (2-way is free on CDNA4).
#define BSWZ(c) ((c) + 4 * ((c) >> 5))
__global__ __launch_bounds__(256) void k_dist(const float* __restrict__ A,
    const float* __restrict__ V, const float* __restrict__ E,
    float* __restrict__ ws) {
  const int z = blockIdx.z;
  const float* X  = z ? V : A;
  const float* xx = ws + (z ? OFF_XX_V : OFF_XX_A);
  const float* ee = ws + OFF_EE;
  float* Dst = ws + (z ? OFF_DV : OFF_DA);

  __shared__ __align__(16) float As[32][128];
  __shared__ __align__(16) float Bs[32][144];

  const int tid = threadIdx.x;
  const int tx = tid & 15;          // col group: cols tx*8..tx*8+7
  const int ty = tid >> 4;          // row group: rows ty*8..ty*8+7
  const int row0 = blockIdx.y * 128;
  const int col0 = blockIdx.x * 128;
  const int bcol = tx * 8 + 4 * (tx >> 2);   // BSWZ(tx*8)

  float acc[8][8] = {};

  for (int kc = 0; kc < 256; kc += 32) {
    // stage: 128 rows x 32 k of A and B; 4 float4 per thread per matrix
    #pragma unroll
    for (int i = 0; i < 4; ++i) {
      int f  = i * 256 + tid;      // 0..1023
      int r  = f >> 3;             // 0..127
      int k4 = (f & 7) << 2;       // 0,4,..,28
      float4 a = *(const float4*)(X + (size_t)(row0 + r) * DD + kc + k4);
      As[k4+0][r] = a.x; As[k4+1][r] = a.y; As[k4+2][r] = a.z; As[k4+3][r] = a.w;
      float4 b = *(const float4*)(E + (size_t)(col0 + r) * DD + kc + k4);
      int rs = BSWZ(r);
      Bs[k4+0][rs] = b.x; Bs[k4+1][rs] = b.y; Bs[k4+2][rs] = b.z; Bs[k4+3][rs] = b.w;
    }
    __syncthreads();
    #pragma unroll 4
    for (int k = 0; k < 32; ++k) {
      float4 a0 = *(const float4*)(&As[k][ty * 8]);
      float4 a1 = *(const float4*)(&As[k][ty * 8 + 4]);
      float4 b0 = *(const float4*)(&Bs[k][bcol]);
      float4 b1 = *(const float4*)(&Bs[k][bcol + 4]);
      float aa[8] = {a0.x, a0.y, a0.z, a0.w, a1.x, a1.y, a1.z, a1.w};
      float bb[8] = {b0.x, b0.y, b0.z, b0.w, b1.x, b1.y, b1.z, b1.w};
      #pragma unroll
      for (int i = 0; i < 8; ++i)
        #pragma unroll
        for (int j = 0; j < 8; ++j)
          acc[i][j] = fmaf(aa[i], bb[j], acc[i][j]);
    }
    __syncthreads();
  }

  float er[8];
  #pragma unroll
  for (int j = 0; j < 8; ++j) er[j] = ee[col0 + tx * 8 + j];
  #pragma unroll
  for (int i = 0; i < 8; ++i) {
    float xri = xx[row0 + ty * 8 + i];
    float o[8];
    #pragma unroll
    for (int j = 0; j < 8; ++j) o[j] = (er[j] + xri) - 2.0f * acc[i][j];
    float* drow = Dst + (size_t)(row0 + ty * 8 + i) * MCB + col0 + tx * 8;
    *(float4*)(drow)     = *(float4*)(&o[0]);
    *(float4*)(drow + 4) = *(float4*)(&o[4]);
  }
}

// ---------------------------------------------------------------------------
// Kernel 3: per-row stats (min/argmin, softmax denominators) + quantize write.
__global__ void k_rowstats(const float* __restrict__ A, const float* __restrict__ V,
                           const float* __restrict__ E, float* __restrict__ ws,
                           float* __restrict__ out) {
  const int z = blockIdx.y;
  const float* Dm = ws + (z ? OFF_DV : OFF_DA);
  const float* X  = z ? V : A;
  float* smin_o = ws + (z ? OFF_SMIN_V : OFF_SMIN_A);
  float* lz1_o  = ws + (z ? OFF_LZ1_V  : OFF_LZ1_A);
  float* iz2_o  = ws + (z ? OFF_IZ2_V  : OFF_IZ2_A);
  int*   idx_o  = (int*)(ws + (z ? OFF_IDX_V : OFF_IDX_A));
  float* qout = out + 1 + (size_t)z * ((size_t)NROWS * DD);

  const int lane = threadIdx.x & 63, wid = threadIdx.x >> 6;
  const int n = blockIdx.x * 4 + wid;
  const float* drow = Dm + (size_t)n * MCB;

  float v[16];
  #pragma unroll
  for (int c = 0; c < 4; ++c) {
    float4 t = *(const float4*)(drow + c * 256 + lane * 4);
    v[c*4+0] = t.x; v[c*4+1] = t.y; v[c*4+2] = t.z; v[c*4+3] = t.w;
  }
  float bv = 3.4e38f; int bi = 0;
  #pragma unroll
  for (int c = 0; c < 4; ++c)
    #pragma unroll
    for (int j = 0; j < 4; ++j) {
      float val = v[c*4+j];
      int m = c * 256 + lane * 4 + j;
      if (val < bv) { bv = val; bi = m; }
    }
  #pragma unroll
  for (int off = 32; off; off >>= 1) {
    float ov = __shfl_xor(bv, off);
    int   oi = __shfl_xor(bi, off);
    if (ov < bv || (ov == bv && oi < bi)) { bv = ov; bi = oi; }
  }
  float smin = sqrtf(fmaxf(bv, 0.0f));
  float z1 = 0.f, z2 = 0.f;
  #pragma unroll
  for (int q = 0; q < 16; ++q) {
    float w = sqrtf(fmaxf(v[q], 0.0f)) - smin;
    z1 += expf(-w);
    z2 += expf(-2.0f * w);
  }
  #pragma unroll
  for (int off = 32; off; off >>= 1) {
    z1 += __shfl_xor(z1, off);
    z2 += __shfl_xor(z2, off);
  }
  if (lane == 0) {
    smin_o[n] = smin;
    lz1_o[n]  = logf(z1);
    iz2_o[n]  = 1.0f / z2;
    idx_o[n]  = bi;
  }
  const float* erow = E + (size_t)bi * DD;
  const float* xrow = X + (size_t)n * DD;
  #pragma unroll
  for (int p = 0; p < 4; ++p) {
    int d0 = p * 64 + lane;
    float xv = xrow[d0];
    float ev = erow[d0];
    qout[(size_t)n * DD + d0] = xv + (ev - xv);
  }
}

// ---------------------------------------------------------------------------
// Kernel 4: S[t,b,c] = sum_m adj_p[b*T+t, m] * logq[c*T+t, m]
__global__ __launch_bounds__(256) void k_sgemm(float* __restrict__ ws) {
  const int z = blockIdx.y;
  const int t = blockIdx.x;
  const float* Dp = ws + (z ? OFF_DV : OFF_DA);
  const float* Dq = ws + (z ? OFF_DA : OFF_DV);
  const float* smin_p = ws + (z ? OFF_SMIN_V : OFF_SMIN_A);
  const float* iz2_p  = ws + (z ? OFF_IZ2_V  : OFF_IZ2_A);
  const float* smin_q = ws + (z ? OFF_SMIN_A : OFF_SMIN_V);
  const float* lz1_q  = ws + (z ? OFF_LZ1_A  : OFF_LZ1_V);
  float* S = ws + (z ? OFF_S2 : OFF_S1);

  __shared__ __align__(16) float PA[64][68];
  __shared__ __align__(16) float LQ[64][68];
  __shared__ float sP[64], izP[64], sQ[64], lzQ[64];

  const int tid = threadIdx.x;
  const int tx = tid & 15, ty = tid >> 4;
  const int lm = tid & 63, wq = tid >> 6;

  if (tid < 64) {
    size_t n = (size_t)tid * TT + t;
    sP[tid] = smin_p[n]; izP[tid] = iz2_p[n];
    sQ[tid] = smin_q[n]; lzQ[tid] = lz1_q[n];
  }
  __syncthreads();

  float acc[4][4] = {};
  for (int mc = 0; mc < MCB; mc += 64) {
    #pragma unroll
    for (int i = 0; i < 16; ++i) {
      int b = i * 4 + wq;
      size_t n = (size_t)b * TT + t;
      float dp = Dp[n * MCB + mc + lm];
      float wp = sqrtf(fmaxf(dp, 0.f)) - sP[b];
      PA[lm][b] = expf(-2.f * wp) * izP[b];
      float dq = Dq[n * MCB + mc + lm];
      float wv = sqrtf(fmaxf(dq, 0.f)) - sQ[b];
      LQ[lm][b] = -wv - lzQ[b];
    }
    __syncthreads();
    #pragma unroll
    for (int mm = 0; mm < 64; ++mm) {
      float4 av = *(const float4*)(&PA[mm][ty << 2]);
      float4 bv = *(const float4*)(&LQ[mm][tx << 2]);
      float aa[4] = {av.x, av.y, av.z, av.w};
      float bb[4] = {bv.x, bv.y, bv.z, bv.w};
      #pragma unroll
      for (int i = 0; i < 4; ++i)
        #pragma unroll
        for (int j = 0; j < 4; ++j)
          acc[i][j] = fmaf(aa[i], bb[j], acc[i][j]);
    }
    __syncthreads();
  }
  #pragma unroll
  for (int i = 0; i < 4; ++i) {
    float4 o = {acc[i][0], acc[i][1], acc[i][2], acc[i][3]};
    *(float4*)(S + ((size_t)t * 64 + (ty << 2) + i) * 64 + (tx << 2)) = o;
  }
}

// ---------------------------------------------------------------------------
// Kernel 5a: partial min over S1/S2
__global__ void k_smin(float* __restrict__ ws) {
  const float* S = ws + (blockIdx.y ? OFF_S2 : OFF_S1);
  float* part = ws + OFF_PART;
  size_t base = (size_t)blockIdx.x * 4096;
  float m = 3.4e38f;
  for (int i = threadIdx.x; i < 4096; i += 256) m = fminf(m, S[base + i]);
  #pragma unroll
  for (int off = 32; off; off >>= 1) m = fminf(m, __shfl_xor(m, off));
  __shared__ float red[4];
  const int lane = threadIdx.x & 63, wid = threadIdx.x >> 6;
  if (lane == 0) red[wid] = m;
  __syncthreads();
  if (threadIdx.x == 0)
    part[blockIdx.y * 128 + blockIdx.x] =
        fminf(fminf(red[0], red[1]), fminf(red[2], red[3]));
}

// Kernel 5b: final max(-S) per tensor
__global__ void k_sfinal(float* __restrict__ ws) {
  const float* part = ws + OFF_PART;
  float* maxv = ws + OFF_MAX;
  const int tens = threadIdx.x >> 7;
  const int i = threadIdx.x & 127;
  float m = part[tens * 128 + i];
  #pragma unroll
  for (int off = 32; off; off >>= 1) m = fminf(m, __shfl_xor(m, off));
  __shared__ float red[4];
  const int lane = threadIdx.x & 63, wid = threadIdx.x >> 6;
  if (lane == 0) red[wid] = m;
  __syncthreads();
  if (threadIdx.x == 0)   maxv[0] = -fminf(red[0], red[1]);
  if (threadIdx.x == 128) maxv[1] = -fminf(red[2], red[3]);
}

// ---------------------------------------------------------------------------
// Kernel 6: loss rows; per-wave register accumulation, per-block partial.
__global__ __launch_bounds__(256) void k_loss(float* __restrict__ ws) {
  const int lane = threadIdx.x & 63, wid = threadIdx.x >> 6;
  const int wglobal = blockIdx.x * 4 + wid;   // 0..1023
  const float* Smax = ws + OFF_MAX;
  double acc = 0.0;
  #pragma unroll 4
  for (int r = 0; r < 16; ++r) {
    int gw = wglobal * 16 + r;                // 0..16383
    int tens = gw >> 13;
    int rem = gw & 8191;                      // t*64 + b
    const float* S = ws + (tens ? OFF_S2 : OFF_S1);
    float maxv = Smax[tens];
    float ev = expf(S[(size_t)rem * 64 + lane] + maxv);
    float sum = ev;
    #pragma unroll
    for (int off = 32; off; off >>= 1) sum += __shfl_xor(sum, off);
    float diag = __shfl(ev, rem & 63);
    if (lane == 0) acc += (double)logf(diag / (sum + 1e-5f));
  }
  __shared__ double red[4];
  if (lane == 0) red[wid] = acc;
  __syncthreads();
  if (threadIdx.x == 0)
    ((double*)(ws + OFF_PACC))[blockIdx.x] = red[0] + red[1] + red[2] + red[3];
}

// Kernel 7: reduce 256 per-block partials, finalize loss
__global__ void k_fin(const float* __restrict__ ws, float* __restrict__ out) {
  const double* p = (const double*)(ws + OFF_PACC);
  const int lane = threadIdx.x & 63, wid = threadIdx.x >> 6;
  double v = p[threadIdx.x];
  #pragma unroll
  for (int off = 32; off; off >>= 1) v += __shfl_xor(v, off);
  __shared__ double red[4];
  if (lane == 0) red[wid] = v;
  __syncthreads();
  if (threadIdx.x == 0)
    out[0] = (float)(-(red[0] + red[1] + red[2] + red[3]) / 16384.0);
}

// ---------------------------------------------------------------------------
extern "C" void kernel_launch(void* const* d_in, const int* in_sizes, int n_in,
                              void* d_out, int out_size, void* d_ws, size_t ws_size,
                              hipStream_t stream) {
  const float* A = (const float*)d_in[0];
  const float* V = (const float*)d_in[1];
  const float* E = (const float*)d_in[2];
  float* out = (float*)d_out;
  float* ws  = (float*)d_ws;

  k_sumsq  <<<dim3(4352), dim3(256), 0, stream>>>(A, V, E, ws);
  k_dist   <<<dim3(8, 64, 2), dim3(256), 0, stream>>>(A, V, E, ws);
  k_rowstats<<<dim3(2048, 2), dim3(256), 0, stream>>>(A, V, E, ws, out);
  k_sgemm  <<<dim3(128, 2), dim3(256), 0, stream>>>(ws);
  k_smin   <<<dim3(128, 2), dim3(256), 0, stream>>>(ws);
  k_sfinal <<<dim3(1), dim3(256), 0, stream>>>(ws);
  k_loss   <<<dim3(256), dim3(256), 0, stream>>>(ws);
  k_fin    <<<dim3(1), dim3(256), 0, stream>>>(ws, out);
}